// Round 2
// baseline (11449.278 us; speedup 1.0000x reference)
//
#include <hip/hip_runtime.h>
#include <cstdint>
#include <cstddef>

#define DIM 2048
#define NHEADS 16
#define HD 128
#define BATCH 4
#define SEQ 2048
#define MROWS (BATCH*SEQ)   // 8192

typedef __attribute__((ext_vector_type(4))) float  f32x4;
typedef __attribute__((ext_vector_type(4))) float  float4v;
typedef __attribute__((ext_vector_type(8))) short  short8;
typedef __attribute__((ext_vector_type(4))) short  short4v;
typedef __attribute__((ext_vector_type(4))) unsigned uint4v;
typedef __attribute__((ext_vector_type(8))) __bf16 bf16x8;

__device__ __forceinline__ unsigned f2bfbits(float f) {
  unsigned u = __builtin_bit_cast(unsigned, f);
  return (u + 0x7FFFu + ((u >> 16) & 1u)) >> 16;
}
__device__ __forceinline__ short f2bf(float f) { return (short)f2bfbits(f); }
__device__ __forceinline__ float bf2f(short s) {
  unsigned u = ((unsigned)(unsigned short)s) << 16;
  return __builtin_bit_cast(float, u);
}
__device__ __forceinline__ f32x4 mfma16(short8 a, short8 b, f32x4 c) {
  return __builtin_amdgcn_mfma_f32_16x16x32_bf16(
      __builtin_bit_cast(bf16x8, a), __builtin_bit_cast(bf16x8, b), c, 0, 0, 0);
}

// ---------------------------------------------------------------- prep: x -> bf16
__global__ __launch_bounds__(256) void k_convert_x(const float* __restrict__ x,
                                                   short* __restrict__ xb) {
  size_t i = ((size_t)blockIdx.x * 256 + threadIdx.x) * 8;
  float4v a = *(const float4v*)(x + i);
  float4v b = *(const float4v*)(x + i + 4);
  short8 o;
  o[0] = f2bf(a[0]); o[1] = f2bf(a[1]); o[2] = f2bf(a[2]); o[3] = f2bf(a[3]);
  o[4] = f2bf(b[0]); o[5] = f2bf(b[1]); o[6] = f2bf(b[2]); o[7] = f2bf(b[3]);
  *(short8*)(xb + i) = o;
}

// ------------------------------------------------- prep: W [K][N] f32 -> Wt [N][K] bf16
__global__ __launch_bounds__(256) void k_transpose_w(
    const float* __restrict__ w0, const float* __restrict__ w1,
    const float* __restrict__ w2, const float* __restrict__ w3,
    short* __restrict__ o0, short* __restrict__ o1,
    short* __restrict__ o2, short* __restrict__ o3) {
  const float* w; short* o;
  switch (blockIdx.z) {
    case 0: w = w0; o = o0; break;
    case 1: w = w1; o = o1; break;
    case 2: w = w2; o = o2; break;
    default: w = w3; o = o3; break;
  }
  __shared__ float tile[32][33];
  int tx = threadIdx.x, ty = threadIdx.y;          // 32 x 8
  int kb = blockIdx.y * 32, nb = blockIdx.x * 32;
#pragma unroll
  for (int i = 0; i < 4; ++i)
    tile[ty + 8 * i][tx] = w[(size_t)(kb + ty + 8 * i) * DIM + nb + tx];
  __syncthreads();
#pragma unroll
  for (int i = 0; i < 4; ++i)
    o[(size_t)(nb + ty + 8 * i) * DIM + kb + tx] = f2bf(tile[tx][ty + 8 * i]);
}

// ---------------------------------------------------------------- GEMM
// C[M=8192][N=2048] = A[M][K=2048] (bf16) @ Bt[N][K] (bf16)^T
// MODE 0: bf16 out scattered to (B,H,S,D)     (q, k)
// MODE 1: bf16 out scattered to (B,H,D,S)     (v, pre-transposed)
// MODE 2: f32 out row-major [M][N]            (final projection)
template<int MODE>
__global__ __launch_bounds__(256) void k_gemm(const short* __restrict__ A,
                                              const short* __restrict__ Bt,
                                              void* __restrict__ outp) {
  __shared__ short As[128][72];
  __shared__ short Bs[128][72];
  const int t = threadIdx.x;
  const int lane = t & 63, wid = t >> 6;
  const int wm = wid >> 1, wn = wid & 1;
  const int gi = lane >> 4, li = lane & 15;
  const int m0 = blockIdx.y * 128, n0 = blockIdx.x * 128;

  f32x4 acc[4][4];
#pragma unroll
  for (int i = 0; i < 4; ++i)
#pragma unroll
    for (int j = 0; j < 4; ++j) acc[i][j] = (f32x4){0.f, 0.f, 0.f, 0.f};

  for (int k0 = 0; k0 < DIM; k0 += 64) {
#pragma unroll
    for (int i = 0; i < 4; ++i) {
      int idx = i * 256 + t;
      int r = idx >> 3, c = (idx & 7) * 8;
      *(short8*)&As[r][c] = *(const short8*)(A + (size_t)(m0 + r) * DIM + k0 + c);
      *(short8*)&Bs[r][c] = *(const short8*)(Bt + (size_t)(n0 + r) * DIM + k0 + c);
    }
    __syncthreads();
#pragma unroll
    for (int kk = 0; kk < 2; ++kk) {
      short8 av[4], bv[4];
#pragma unroll
      for (int i = 0; i < 4; ++i) {
        av[i] = *(const short8*)&As[64 * wm + 16 * i + li][kk * 32 + 8 * gi];
        bv[i] = *(const short8*)&Bs[64 * wn + 16 * i + li][kk * 32 + 8 * gi];
      }
#pragma unroll
      for (int i = 0; i < 4; ++i)
#pragma unroll
        for (int j = 0; j < 4; ++j)
          acc[i][j] = mfma16(av[i], bv[j], acc[i][j]);
    }
    __syncthreads();
  }

  if (MODE == 2) {
    float* O = (float*)outp;
#pragma unroll
    for (int i = 0; i < 4; ++i)
#pragma unroll
      for (int j = 0; j < 4; ++j)
#pragma unroll
        for (int r = 0; r < 4; ++r) {
          int gm = m0 + 64 * wm + 16 * i + 4 * gi + r;
          int gn = n0 + 64 * wn + 16 * j + li;
          O[(size_t)gm * DIM + gn] = acc[i][j][r];
        }
  } else if (MODE == 0) {
    short* O = (short*)outp;
#pragma unroll
    for (int i = 0; i < 4; ++i)
#pragma unroll
      for (int j = 0; j < 4; ++j)
#pragma unroll
        for (int r = 0; r < 4; ++r) {
          int gm = m0 + 64 * wm + 16 * i + 4 * gi + r;
          int gn = n0 + 64 * wn + 16 * j + li;
          int b = gm >> 11, s = gm & 2047, h = gn >> 7, d = gn & 127;
          O[((size_t)(b * NHEADS + h) * SEQ + s) * HD + d] = f2bf(acc[i][j][r]);
        }
  } else {  // MODE 1: (B,H,D,S), 4 consecutive s pack to one 8B store
    short* O = (short*)outp;
#pragma unroll
    for (int i = 0; i < 4; ++i)
#pragma unroll
      for (int j = 0; j < 4; ++j) {
        int gm0 = m0 + 64 * wm + 16 * i + 4 * gi;
        int gn = n0 + 64 * wn + 16 * j + li;
        int b = gm0 >> 11, s0 = gm0 & 2047, h = gn >> 7, d = gn & 127;
        short4v pk;
#pragma unroll
        for (int r = 0; r < 4; ++r) pk[r] = f2bf(acc[i][j][r]);
        *(short4v*)&O[((size_t)(b * NHEADS + h) * HD + d) * SEQ + s0] = pk;
      }
  }
}

// ---------------------------------------------------------------- RoPE in-place on Q,K (B,H,S,D)
__global__ __launch_bounds__(256) void k_rope(short* __restrict__ Q, short* __restrict__ K,
                                              const float* __restrict__ cosg,
                                              const float* __restrict__ sing) {
  int gid = blockIdx.x * 256 + threadIdx.x;       // 64*2048*16
  int bh = gid >> 15, rem = gid & 32767;
  int s = rem >> 4, dg = rem & 15;
  size_t base = ((size_t)bh * SEQ + s) * HD + dg * 4;
  float4v c = *(const float4v*)(cosg + s * 64 + dg * 4);
  float4v sn = *(const float4v*)(sing + s * 64 + dg * 4);
  short4v q1 = *(short4v*)(Q + base), q2 = *(short4v*)(Q + base + 64);
  short4v k1 = *(short4v*)(K + base), k2 = *(short4v*)(K + base + 64);
  short4v oq1, oq2, ok1, ok2;
#pragma unroll
  for (int j = 0; j < 4; ++j) {
    float a = bf2f(q1[j]), b = bf2f(q2[j]);
    oq1[j] = f2bf(a * c[j] - b * sn[j]);
    oq2[j] = f2bf(b * c[j] + a * sn[j]);
    float ak = bf2f(k1[j]), bk = bf2f(k2[j]);
    ok1[j] = f2bf(ak * c[j] - bk * sn[j]);
    ok2[j] = f2bf(bk * c[j] + ak * sn[j]);
  }
  *(short4v*)(Q + base) = oq1; *(short4v*)(Q + base + 64) = oq2;
  *(short4v*)(K + base) = ok1; *(short4v*)(K + base + 64) = ok2;
}

// ---------------------------------------------------------------- causal flash attention
// Q,K: (B,H,S,D) bf16 roped; V: (B,H,D,S) bf16; O: (B,S,H*D) bf16
// Balanced pairing: block x = i in 0..15 owns q-tiles {i, 31-i}; every wave holds
// 16 rows of BOTH tiles, so one K/V ds_read feeds 2 MFMAs. Double-buffered LDS,
// register prefetch of next K/V tile, ONE barrier per tile.
// grid (16, B*H), 256 thr = 4 waves.
__device__ __forceinline__ void sm_update(const f32x4 s[4], bool lastT, int k0, int mrow,
                                          int gi, int li, int srcA, int srcB, bool hig,
                                          float& mx, float& lsum, f32x4* o,
                                          short8& pb0, short8& pb1) {
  const float sc = 0.08838834764831843f;          // 1/sqrt(128)
  float p[4][4];
  float pmax = -1e30f;
#pragma unroll
  for (int af = 0; af < 4; ++af)
#pragma unroll
    for (int r = 0; r < 4; ++r) {
      float v = s[af][r] * sc;
      if (lastT && (k0 + 16 * af + 4 * gi + r > mrow)) v = -1e30f;
      p[af][r] = v;
      pmax = fmaxf(pmax, v);
    }
  pmax = fmaxf(pmax, __shfl_xor(pmax, 16));
  pmax = fmaxf(pmax, __shfl_xor(pmax, 32));
  float mnew = fmaxf(mx, pmax);
  float alpha = __expf(mx - mnew);
  float psum = 0.f;
#pragma unroll
  for (int af = 0; af < 4; ++af)
#pragma unroll
    for (int r = 0; r < 4; ++r) {
      float e = __expf(p[af][r] - mnew);
      p[af][r] = e;
      psum += e;
    }
  psum += __shfl_xor(psum, 16);
  psum += __shfl_xor(psum, 32);
  lsum = lsum * alpha + psum;
  mx = mnew;
#pragma unroll
  for (int d = 0; d < 8; ++d) o[d] *= alpha;

  unsigned plo[4], phi[4];
#pragma unroll
  for (int af = 0; af < 4; ++af) {
    plo[af] = f2bfbits(p[af][0]) | (f2bfbits(p[af][1]) << 16);
    phi[af] = f2bfbits(p[af][2]) | (f2bfbits(p[af][3]) << 16);
  }
#pragma unroll
  for (int kk2 = 0; kk2 < 2; ++kk2) {
    unsigned aAlo = (unsigned)__shfl((int)plo[2 * kk2], srcA);
    unsigned aAhi = (unsigned)__shfl((int)phi[2 * kk2], srcA);
    unsigned aBlo = (unsigned)__shfl((int)plo[2 * kk2 + 1], srcA);
    unsigned aBhi = (unsigned)__shfl((int)phi[2 * kk2 + 1], srcA);
    unsigned bAlo = (unsigned)__shfl((int)plo[2 * kk2], srcB);
    unsigned bAhi = (unsigned)__shfl((int)phi[2 * kk2], srcB);
    unsigned bBlo = (unsigned)__shfl((int)plo[2 * kk2 + 1], srcB);
    unsigned bBhi = (unsigned)__shfl((int)phi[2 * kk2 + 1], srcB);
    uint4v dws;
    dws[0] = hig ? aBlo : aAlo;
    dws[1] = hig ? aBhi : aAhi;
    dws[2] = hig ? bBlo : bAlo;
    dws[3] = hig ? bBhi : bAhi;
    if (kk2 == 0) pb0 = __builtin_bit_cast(short8, dws);
    else          pb1 = __builtin_bit_cast(short8, dws);
  }
}

__global__ __launch_bounds__(256, 2) void k_flash(const short* __restrict__ Qg,
                                                  const short* __restrict__ Kg,
                                                  const short* __restrict__ Vg,
                                                  short* __restrict__ Og) {
  __shared__ short Ks[2][64][136];
  __shared__ short Vs[2][128][72];
  const int t = threadIdx.x, lane = t & 63, wid = t >> 6;
  const int gi = lane >> 4, li = lane & 15;
  const int bh = blockIdx.y;
  const int ip = blockIdx.x;                      // 0..15 : q-tiles {ip, 31-ip}
  const int nt = 32 - ip;                         // k-tiles needed by tile B
  const int q0a = 64 * ip, q0b = 64 * (31 - ip);
  const short* Qb = Qg + (size_t)bh * SEQ * HD;
  const short* Kb = Kg + (size_t)bh * SEQ * HD;
  const short* Vb = Vg + (size_t)bh * HD * SEQ;
  const int mrowA = q0a + wid * 16 + li;
  const int mrowB = q0b + wid * 16 + li;

  short8 qA[4], qB[4];
#pragma unroll
  for (int kk = 0; kk < 4; ++kk) {
    qA[kk] = *(const short8*)(Qb + (size_t)mrowA * HD + kk * 32 + 8 * gi);
    qB[kk] = *(const short8*)(Qb + (size_t)mrowB * HD + kk * 32 + 8 * gi);
  }

  f32x4 oA[8], oB[8];
#pragma unroll
  for (int d = 0; d < 8; ++d) {
    oA[d] = (f32x4){0.f, 0.f, 0.f, 0.f};
    oB[d] = (f32x4){0.f, 0.f, 0.f, 0.f};
  }
  float mxA = -1e30f, lsA = 0.f, mxB = -1e30f, lsB = 0.f;
  const int srcA = li | ((lane & 16) << 1);
  const int srcB = srcA + 16;
  const bool hig = (lane & 32) != 0;

  auto LOADK = [&](int j, int k0) {
    int idx = j * 256 + t;
    return *(const short8*)(Kb + (size_t)(k0 + (idx >> 4)) * HD + (idx & 15) * 8);
  };
  auto LOADV = [&](int j, int k0) {
    int idx = j * 256 + t;
    return *(const short8*)(Vb + (size_t)(idx >> 3) * SEQ + k0 + (idx & 7) * 8);
  };

  short8 pk0, pk1, pk2, pk3, pv0, pv1, pv2, pv3;
  // prologue: stage tile 0 into buffer 0
  pk0 = LOADK(0, 0); pk1 = LOADK(1, 0); pk2 = LOADK(2, 0); pk3 = LOADK(3, 0);
  pv0 = LOADV(0, 0); pv1 = LOADV(1, 0); pv2 = LOADV(2, 0); pv3 = LOADV(3, 0);
  {
    int i0 = t, i1 = 256 + t, i2 = 512 + t, i3 = 768 + t;
    *(short8*)&Ks[0][i0 >> 4][(i0 & 15) * 8] = pk0;
    *(short8*)&Ks[0][i1 >> 4][(i1 & 15) * 8] = pk1;
    *(short8*)&Ks[0][i2 >> 4][(i2 & 15) * 8] = pk2;
    *(short8*)&Ks[0][i3 >> 4][(i3 & 15) * 8] = pk3;
    *(short8*)&Vs[0][i0 >> 3][(i0 & 7) * 8] = pv0;
    *(short8*)&Vs[0][i1 >> 3][(i1 & 7) * 8] = pv1;
    *(short8*)&Vs[0][i2 >> 3][(i2 & 7) * 8] = pv2;
    *(short8*)&Vs[0][i3 >> 3][(i3 & 7) * 8] = pv3;
  }
  __syncthreads();

  for (int tt = 0; tt < nt; ++tt) {
    const int cb = tt & 1;
    const bool pf = (tt + 1 < nt);
    if (pf) {                                     // issue next tile's loads NOW
      int k0n = (tt + 1) * 64;
      pk0 = LOADK(0, k0n); pk1 = LOADK(1, k0n); pk2 = LOADK(2, k0n); pk3 = LOADK(3, k0n);
      pv0 = LOADV(0, k0n); pv1 = LOADV(1, k0n); pv2 = LOADV(2, k0n); pv3 = LOADV(3, k0n);
    }
    const int k0 = tt * 64;
    const bool aAct = (tt <= ip);

    f32x4 sA[4], sB[4];
#pragma unroll
    for (int af = 0; af < 4; ++af) {
      sA[af] = (f32x4){0.f, 0.f, 0.f, 0.f};
      sB[af] = (f32x4){0.f, 0.f, 0.f, 0.f};
    }
#pragma unroll
    for (int kk = 0; kk < 4; ++kk)
#pragma unroll
      for (int af = 0; af < 4; ++af) {
        short8 kf = *(const short8*)&Ks[cb][16 * af + li][kk * 32 + 8 * gi];
        if (aAct) sA[af] = mfma16(kf, qA[kk], sA[af]);
        sB[af] = mfma16(kf, qB[kk], sB[af]);
      }

    short8 paA0 = {}, paA1 = {}, paB0, paB1;
    if (aAct)
      sm_update(sA, tt == ip, k0, mrowA, gi, li, srcA, srcB, hig, mxA, lsA, oA, paA0, paA1);
    sm_update(sB, tt == nt - 1, k0, mrowB, gi, li, srcA, srcB, hig, mxB, lsB, oB, paB0, paB1);

#pragma unroll
    for (int kk2 = 0; kk2 < 2; ++kk2)
#pragma unroll
      for (int d = 0; d < 8; ++d) {
        short8 vf = *(const short8*)&Vs[cb][16 * d + li][kk2 * 32 + 8 * gi];
        if (aAct) oA[d] = mfma16(vf, kk2 ? paA1 : paA0, oA[d]);
        oB[d] = mfma16(vf, kk2 ? paB1 : paB0, oB[d]);
      }

    if (pf) {                                     // write prefetched tile to other buffer
      int nb = cb ^ 1;
      int i0 = t, i1 = 256 + t, i2 = 512 + t, i3 = 768 + t;
      *(short8*)&Ks[nb][i0 >> 4][(i0 & 15) * 8] = pk0;
      *(short8*)&Ks[nb][i1 >> 4][(i1 & 15) * 8] = pk1;
      *(short8*)&Ks[nb][i2 >> 4][(i2 & 15) * 8] = pk2;
      *(short8*)&Ks[nb][i3 >> 4][(i3 & 15) * 8] = pk3;
      *(short8*)&Vs[nb][i0 >> 3][(i0 & 7) * 8] = pv0;
      *(short8*)&Vs[nb][i1 >> 3][(i1 & 7) * 8] = pv1;
      *(short8*)&Vs[nb][i2 >> 3][(i2 & 7) * 8] = pv2;
      *(short8*)&Vs[nb][i3 >> 3][(i3 & 7) * 8] = pv3;
    }
    __syncthreads();
  }

  const int bq = bh >> 4, h = bh & 15;
  {
    const float inv = 1.0f / lsA;
    const size_t obase = ((size_t)bq * SEQ + mrowA) * DIM + h * HD;
#pragma unroll
    for (int d = 0; d < 8; ++d) {
      short4v st;
#pragma unroll
      for (int r = 0; r < 4; ++r) st[r] = f2bf(oA[d][r] * inv);
      *(short4v*)&Og[obase + d * 16 + 4 * gi] = st;
    }
  }
  {
    const float inv = 1.0f / lsB;
    const size_t obase = ((size_t)bq * SEQ + mrowB) * DIM + h * HD;
#pragma unroll
    for (int d = 0; d < 8; ++d) {
      short4v st;
#pragma unroll
      for (int r = 0; r < 4; ++r) st[r] = f2bf(oB[d][r] * inv);
      *(short4v*)&Og[obase + d * 16 + 4 * gi] = st;
    }
  }
}

// ---------------------------------------------------------------- launcher
extern "C" void kernel_launch(void* const* d_in, const int* in_sizes, int n_in,
                              void* d_out, int out_size, void* d_ws, size_t ws_size,
                              hipStream_t stream) {
  (void)in_sizes; (void)n_in; (void)out_size;
  const float* x    = (const float*)d_in[0];
  const float* cosg = (const float*)d_in[1];
  const float* sing = (const float*)d_in[2];
  const float* wq   = (const float*)d_in[3];
  const float* wk   = (const float*)d_in[4];
  const float* wv   = (const float*)d_in[5];
  const float* wo   = (const float*)d_in[6];

  const size_t SZ = (size_t)MROWS * DIM * 2;      // 33,554,432 B
  char* ws = (char*)d_ws;
  short* xb  = (short*)ws;                        // region 0, later reused as attn-out O
  short* wqT = (short*)(ws + SZ);
  short* wkT = wqT + (size_t)DIM * DIM;
  short* wvT = wkT + (size_t)DIM * DIM;
  short* woT = wvT + (size_t)DIM * DIM;
  short *Qp, *Kp, *Vp;
  if (ws_size >= 5 * SZ) {
    Qp = (short*)(ws + 2 * SZ);
    Kp = (short*)(ws + 3 * SZ);
    Vp = (short*)(ws + 4 * SZ);
  } else {                                        // park Q,K in d_out (overwritten at the end)
    Qp = (short*)d_out;
    Kp = (short*)d_out + SZ / 2;
    Vp = (short*)(ws + 2 * SZ);
  }
  short* Ob = xb;                                 // alias: xb dead after QKV GEMMs

  k_convert_x<<<8192, 256, 0, stream>>>(x, xb);
  k_transpose_w<<<dim3(64, 64, 4), dim3(32, 8), 0, stream>>>(wq, wk, wv, wo,
                                                             wqT, wkT, wvT, woT);
  k_gemm<0><<<dim3(16, 64), 256, 0, stream>>>(xb, wqT, Qp);
  k_gemm<0><<<dim3(16, 64), 256, 0, stream>>>(xb, wkT, Kp);
  k_gemm<1><<<dim3(16, 64), 256, 0, stream>>>(xb, wvT, Vp);
  k_rope<<<8192, 256, 0, stream>>>(Qp, Kp, cosg, sing);
  k_flash<<<dim3(16, 64), 256, 0, stream>>>(Qp, Kp, Vp, Ob);
  k_gemm<2><<<dim3(16, 64), 256, 0, stream>>>(Ob, woT, d_out);
}

// Round 3
// 569.157 us; speedup vs baseline: 20.1162x; 20.1162x over previous
//
#include <hip/hip_runtime.h>
#include <cstdint>
#include <cstddef>

#define DIM 2048
#define NHEADS 16
#define HD 128
#define BATCH 4
#define SEQ 2048
#define MROWS (BATCH*SEQ)   // 8192

typedef __attribute__((ext_vector_type(4))) float  f32x4;
typedef __attribute__((ext_vector_type(4))) float  float4v;
typedef __attribute__((ext_vector_type(8))) short  short8;
typedef __attribute__((ext_vector_type(4))) short  short4v;
typedef __attribute__((ext_vector_type(4))) unsigned uint4v;
typedef __attribute__((ext_vector_type(8))) __bf16 bf16x8;

__device__ __forceinline__ unsigned f2bfbits(float f) {
  unsigned u = __builtin_bit_cast(unsigned, f);
  return (u + 0x7FFFu + ((u >> 16) & 1u)) >> 16;
}
__device__ __forceinline__ short f2bf(float f) { return (short)f2bfbits(f); }
__device__ __forceinline__ float bf2f(short s) {
  unsigned u = ((unsigned)(unsigned short)s) << 16;
  return __builtin_bit_cast(float, u);
}
__device__ __forceinline__ f32x4 mfma16(short8 a, short8 b, f32x4 c) {
  return __builtin_amdgcn_mfma_f32_16x16x32_bf16(
      __builtin_bit_cast(bf16x8, a), __builtin_bit_cast(bf16x8, b), c, 0, 0, 0);
}

// ---------------------------------------------------------------- prep: x -> bf16
__global__ __launch_bounds__(256) void k_convert_x(const float* __restrict__ x,
                                                   short* __restrict__ xb) {
  size_t i = ((size_t)blockIdx.x * 256 + threadIdx.x) * 8;
  float4v a = *(const float4v*)(x + i);
  float4v b = *(const float4v*)(x + i + 4);
  short8 o;
  o[0] = f2bf(a[0]); o[1] = f2bf(a[1]); o[2] = f2bf(a[2]); o[3] = f2bf(a[3]);
  o[4] = f2bf(b[0]); o[5] = f2bf(b[1]); o[6] = f2bf(b[2]); o[7] = f2bf(b[3]);
  *(short8*)(xb + i) = o;
}

// ------------------------------------------------- prep: W [K][N] f32 -> Wt [N][K] bf16
__global__ __launch_bounds__(256) void k_transpose_w(
    const float* __restrict__ w0, const float* __restrict__ w1,
    const float* __restrict__ w2, const float* __restrict__ w3,
    short* __restrict__ o0, short* __restrict__ o1,
    short* __restrict__ o2, short* __restrict__ o3) {
  const float* w; short* o;
  switch (blockIdx.z) {
    case 0: w = w0; o = o0; break;
    case 1: w = w1; o = o1; break;
    case 2: w = w2; o = o2; break;
    default: w = w3; o = o3; break;
  }
  __shared__ float tile[32][33];
  int tx = threadIdx.x, ty = threadIdx.y;          // 32 x 8
  int kb = blockIdx.y * 32, nb = blockIdx.x * 32;
#pragma unroll
  for (int i = 0; i < 4; ++i)
    tile[ty + 8 * i][tx] = w[(size_t)(kb + ty + 8 * i) * DIM + nb + tx];
  __syncthreads();
#pragma unroll
  for (int i = 0; i < 4; ++i)
    o[(size_t)(nb + ty + 8 * i) * DIM + kb + tx] = f2bf(tile[tx][ty + 8 * i]);
}

// ---------------------------------------------------------------- GEMM
// C[M=8192][N=2048] = A[M][K=2048] (bf16) @ Bt[N][K] (bf16)^T
// MODE 0: bf16 out scattered to (B,H,S,D)     (q, k)
// MODE 1: bf16 out scattered to (B,H,D,S)     (v, pre-transposed)
// MODE 2: f32 out row-major [M][N]            (final projection)
template<int MODE>
__global__ __launch_bounds__(256) void k_gemm(const short* __restrict__ A,
                                              const short* __restrict__ Bt,
                                              void* __restrict__ outp) {
  __shared__ short As[128][72];
  __shared__ short Bs[128][72];
  const int t = threadIdx.x;
  const int lane = t & 63, wid = t >> 6;
  const int wm = wid >> 1, wn = wid & 1;
  const int gi = lane >> 4, li = lane & 15;
  const int m0 = blockIdx.y * 128, n0 = blockIdx.x * 128;

  f32x4 acc[4][4];
#pragma unroll
  for (int i = 0; i < 4; ++i)
#pragma unroll
    for (int j = 0; j < 4; ++j) acc[i][j] = (f32x4){0.f, 0.f, 0.f, 0.f};

  for (int k0 = 0; k0 < DIM; k0 += 64) {
#pragma unroll
    for (int i = 0; i < 4; ++i) {
      int idx = i * 256 + t;
      int r = idx >> 3, c = (idx & 7) * 8;
      *(short8*)&As[r][c] = *(const short8*)(A + (size_t)(m0 + r) * DIM + k0 + c);
      *(short8*)&Bs[r][c] = *(const short8*)(Bt + (size_t)(n0 + r) * DIM + k0 + c);
    }
    __syncthreads();
#pragma unroll
    for (int kk = 0; kk < 2; ++kk) {
      short8 av[4], bv[4];
#pragma unroll
      for (int i = 0; i < 4; ++i) {
        av[i] = *(const short8*)&As[64 * wm + 16 * i + li][kk * 32 + 8 * gi];
        bv[i] = *(const short8*)&Bs[64 * wn + 16 * i + li][kk * 32 + 8 * gi];
      }
#pragma unroll
      for (int i = 0; i < 4; ++i)
#pragma unroll
        for (int j = 0; j < 4; ++j)
          acc[i][j] = mfma16(av[i], bv[j], acc[i][j]);
    }
    __syncthreads();
  }

  if (MODE == 2) {
    float* O = (float*)outp;
#pragma unroll
    for (int i = 0; i < 4; ++i)
#pragma unroll
      for (int j = 0; j < 4; ++j)
#pragma unroll
        for (int r = 0; r < 4; ++r) {
          int gm = m0 + 64 * wm + 16 * i + 4 * gi + r;
          int gn = n0 + 64 * wn + 16 * j + li;
          O[(size_t)gm * DIM + gn] = acc[i][j][r];
        }
  } else if (MODE == 0) {
    short* O = (short*)outp;
#pragma unroll
    for (int i = 0; i < 4; ++i)
#pragma unroll
      for (int j = 0; j < 4; ++j)
#pragma unroll
        for (int r = 0; r < 4; ++r) {
          int gm = m0 + 64 * wm + 16 * i + 4 * gi + r;
          int gn = n0 + 64 * wn + 16 * j + li;
          int b = gm >> 11, s = gm & 2047, h = gn >> 7, d = gn & 127;
          O[((size_t)(b * NHEADS + h) * SEQ + s) * HD + d] = f2bf(acc[i][j][r]);
        }
  } else {  // MODE 1: (B,H,D,S), 4 consecutive s pack to one 8B store
    short* O = (short*)outp;
#pragma unroll
    for (int i = 0; i < 4; ++i)
#pragma unroll
      for (int j = 0; j < 4; ++j) {
        int gm0 = m0 + 64 * wm + 16 * i + 4 * gi;
        int gn = n0 + 64 * wn + 16 * j + li;
        int b = gm0 >> 11, s0 = gm0 & 2047, h = gn >> 7, d = gn & 127;
        short4v pk;
#pragma unroll
        for (int r = 0; r < 4; ++r) pk[r] = f2bf(acc[i][j][r]);
        *(short4v*)&O[((size_t)(b * NHEADS + h) * HD + d) * SEQ + s0] = pk;
      }
  }
}

// ---------------------------------------------------------------- RoPE in-place on Q,K (B,H,S,D)
__global__ __launch_bounds__(256) void k_rope(short* __restrict__ Q, short* __restrict__ K,
                                              const float* __restrict__ cosg,
                                              const float* __restrict__ sing) {
  int gid = blockIdx.x * 256 + threadIdx.x;       // 64*2048*16
  int bh = gid >> 15, rem = gid & 32767;
  int s = rem >> 4, dg = rem & 15;
  size_t base = ((size_t)bh * SEQ + s) * HD + dg * 4;
  float4v c = *(const float4v*)(cosg + s * 64 + dg * 4);
  float4v sn = *(const float4v*)(sing + s * 64 + dg * 4);
  short4v q1 = *(short4v*)(Q + base), q2 = *(short4v*)(Q + base + 64);
  short4v k1 = *(short4v*)(K + base), k2 = *(short4v*)(K + base + 64);
  short4v oq1, oq2, ok1, ok2;
#pragma unroll
  for (int j = 0; j < 4; ++j) {
    float a = bf2f(q1[j]), b = bf2f(q2[j]);
    oq1[j] = f2bf(a * c[j] - b * sn[j]);
    oq2[j] = f2bf(b * c[j] + a * sn[j]);
    float ak = bf2f(k1[j]), bk = bf2f(k2[j]);
    ok1[j] = f2bf(ak * c[j] - bk * sn[j]);
    ok2[j] = f2bf(bk * c[j] + ak * sn[j]);
  }
  *(short4v*)(Q + base) = oq1; *(short4v*)(Q + base + 64) = oq2;
  *(short4v*)(K + base) = ok1; *(short4v*)(K + base + 64) = ok2;
}

// ---------------------------------------------------------------- causal flash attention
// Q,K: (B,H,S,D) bf16 roped; V: (B,H,D,S) bf16; O: (B,S,H*D) bf16
// Round-1 structure (76 VGPR, no spill) + LPT dispatch: flattened grid 2048,
// id -> ip = 31 - id/64 (heavy blocks FIRST), bh = id & 63. Block does ip+1
// KV tiles. s_setprio(1) around MFMA clusters (independent blocks at
// different phases -> scheduler can favor MFMA waves).
__global__ __launch_bounds__(256) void k_flash(const short* __restrict__ Qg,
                                               const short* __restrict__ Kg,
                                               const short* __restrict__ Vg,
                                               short* __restrict__ Og) {
  __shared__ short Ks[64][136];
  __shared__ short Vs[128][72];
  const int t = threadIdx.x, lane = t & 63, wid = t >> 6;
  const int gi = lane >> 4, li = lane & 15;
  const int id = blockIdx.x;
  const int ip = 31 - (id >> 6);                  // q-tile index, heavy-first
  const int bh = id & 63;
  const int q0 = ip * 64;
  const short* Qb = Qg + (size_t)bh * SEQ * HD;
  const short* Kb = Kg + (size_t)bh * SEQ * HD;
  const short* Vb = Vg + (size_t)bh * HD * SEQ;
  const int mrow = q0 + wid * 16 + li;            // this lane's q row

  short8 qb[4];
#pragma unroll
  for (int kk = 0; kk < 4; ++kk)
    qb[kk] = *(const short8*)(Qb + (size_t)mrow * HD + kk * 32 + 8 * gi);

  f32x4 o[8];
#pragma unroll
  for (int d = 0; d < 8; ++d) o[d] = (f32x4){0.f, 0.f, 0.f, 0.f};
  float mx = -1e30f, lsum = 0.f;
  const int nt = ip + 1;
  const int srcA = li | ((lane & 16) << 1);       // (m, 2*(g&1))
  const int srcB = srcA + 16;
  const bool hig = (lane & 32) != 0;

  for (int tt = 0; tt < nt; ++tt) {
    const int k0 = tt * 64;
#pragma unroll
    for (int i = 0; i < 4; ++i) {
      int idx = i * 256 + t;
      { int r = idx >> 4, c = (idx & 15) * 8;
        *(short8*)&Ks[r][c] = *(const short8*)(Kb + (size_t)(k0 + r) * HD + c); }
      { int r = idx >> 3, c = (idx & 7) * 8;
        *(short8*)&Vs[r][c] = *(const short8*)(Vb + (size_t)r * SEQ + k0 + c); }
    }
    __syncthreads();

    f32x4 sacc[4];
#pragma unroll
    for (int af = 0; af < 4; ++af) sacc[af] = (f32x4){0.f, 0.f, 0.f, 0.f};
    __builtin_amdgcn_s_setprio(1);
#pragma unroll
    for (int kk = 0; kk < 4; ++kk)
#pragma unroll
      for (int af = 0; af < 4; ++af) {
        short8 kf = *(const short8*)&Ks[16 * af + li][kk * 32 + 8 * gi];
        sacc[af] = mfma16(kf, qb[kk], sacc[af]);
      }
    __builtin_amdgcn_s_setprio(0);

    const float sc = 0.08838834764831843f;        // 1/sqrt(128)
    float p[4][4];
    float pmax = -1e30f;
    const bool last = (tt == nt - 1);
#pragma unroll
    for (int af = 0; af < 4; ++af)
#pragma unroll
      for (int r = 0; r < 4; ++r) {
        float v = sacc[af][r] * sc;
        if (last && (k0 + 16 * af + 4 * gi + r > mrow)) v = -1e30f;
        p[af][r] = v;
        pmax = fmaxf(pmax, v);
      }
    pmax = fmaxf(pmax, __shfl_xor(pmax, 16));
    pmax = fmaxf(pmax, __shfl_xor(pmax, 32));
    float mnew = fmaxf(mx, pmax);
    float alpha = __expf(mx - mnew);
    float psum = 0.f;
#pragma unroll
    for (int af = 0; af < 4; ++af)
#pragma unroll
      for (int r = 0; r < 4; ++r) {
        float e = __expf(p[af][r] - mnew);
        p[af][r] = e;
        psum += e;
      }
    psum += __shfl_xor(psum, 16);
    psum += __shfl_xor(psum, 32);
    lsum = lsum * alpha + psum;
    mx = mnew;
#pragma unroll
    for (int d = 0; d < 8; ++d) o[d] *= alpha;

    unsigned plo[4], phi[4];
#pragma unroll
    for (int af = 0; af < 4; ++af) {
      plo[af] = f2bfbits(p[af][0]) | (f2bfbits(p[af][1]) << 16);
      phi[af] = f2bfbits(p[af][2]) | (f2bfbits(p[af][3]) << 16);
    }
#pragma unroll
    for (int kk2 = 0; kk2 < 2; ++kk2) {
      unsigned aAlo = (unsigned)__shfl((int)plo[2 * kk2], srcA);
      unsigned aAhi = (unsigned)__shfl((int)phi[2 * kk2], srcA);
      unsigned aBlo = (unsigned)__shfl((int)plo[2 * kk2 + 1], srcA);
      unsigned aBhi = (unsigned)__shfl((int)phi[2 * kk2 + 1], srcA);
      unsigned bAlo = (unsigned)__shfl((int)plo[2 * kk2], srcB);
      unsigned bAhi = (unsigned)__shfl((int)phi[2 * kk2], srcB);
      unsigned bBlo = (unsigned)__shfl((int)plo[2 * kk2 + 1], srcB);
      unsigned bBhi = (unsigned)__shfl((int)phi[2 * kk2 + 1], srcB);
      uint4v dws;
      dws[0] = hig ? aBlo : aAlo;
      dws[1] = hig ? aBhi : aAhi;
      dws[2] = hig ? bBlo : bAlo;
      dws[3] = hig ? bBhi : bAhi;
      short8 pbf = __builtin_bit_cast(short8, dws);
      __builtin_amdgcn_s_setprio(1);
#pragma unroll
      for (int d = 0; d < 8; ++d) {
        short8 vf = *(const short8*)&Vs[16 * d + li][kk2 * 32 + 8 * gi];
        o[d] = mfma16(vf, pbf, o[d]);
      }
      __builtin_amdgcn_s_setprio(0);
    }
    __syncthreads();
  }

  const float inv = 1.0f / lsum;
  const int b = bh >> 4, h = bh & 15;
  const size_t obase = ((size_t)b * SEQ + mrow) * DIM + h * HD;
#pragma unroll
  for (int d = 0; d < 8; ++d) {
    short4v st;
#pragma unroll
    for (int r = 0; r < 4; ++r) st[r] = f2bf(o[d][r] * inv);
    *(short4v*)&Og[obase + d * 16 + 4 * gi] = st;
  }
}

// ---------------------------------------------------------------- launcher
extern "C" void kernel_launch(void* const* d_in, const int* in_sizes, int n_in,
                              void* d_out, int out_size, void* d_ws, size_t ws_size,
                              hipStream_t stream) {
  (void)in_sizes; (void)n_in; (void)out_size;
  const float* x    = (const float*)d_in[0];
  const float* cosg = (const float*)d_in[1];
  const float* sing = (const float*)d_in[2];
  const float* wq   = (const float*)d_in[3];
  const float* wk   = (const float*)d_in[4];
  const float* wv   = (const float*)d_in[5];
  const float* wo   = (const float*)d_in[6];

  const size_t SZ = (size_t)MROWS * DIM * 2;      // 33,554,432 B
  char* ws = (char*)d_ws;
  short* xb  = (short*)ws;                        // region 0, later reused as attn-out O
  short* wqT = (short*)(ws + SZ);
  short* wkT = wqT + (size_t)DIM * DIM;
  short* wvT = wkT + (size_t)DIM * DIM;
  short* woT = wvT + (size_t)DIM * DIM;
  short *Qp, *Kp, *Vp;
  if (ws_size >= 5 * SZ) {
    Qp = (short*)(ws + 2 * SZ);
    Kp = (short*)(ws + 3 * SZ);
    Vp = (short*)(ws + 4 * SZ);
  } else {                                        // park Q,K in d_out (overwritten at the end)
    Qp = (short*)d_out;
    Kp = (short*)d_out + SZ / 2;
    Vp = (short*)(ws + 2 * SZ);
  }
  short* Ob = xb;                                 // alias: xb dead after QKV GEMMs

  k_convert_x<<<8192, 256, 0, stream>>>(x, xb);
  k_transpose_w<<<dim3(64, 64, 4), dim3(32, 8), 0, stream>>>(wq, wk, wv, wo,
                                                             wqT, wkT, wvT, woT);
  k_gemm<0><<<dim3(16, 64), 256, 0, stream>>>(xb, wqT, Qp);
  k_gemm<0><<<dim3(16, 64), 256, 0, stream>>>(xb, wkT, Kp);
  k_gemm<1><<<dim3(16, 64), 256, 0, stream>>>(xb, wvT, Vp);
  k_rope<<<8192, 256, 0, stream>>>(Qp, Kp, cosg, sing);
  k_flash<<<2048, 256, 0, stream>>>(Qp, Kp, Vp, Ob);
  k_gemm<2><<<dim3(16, 64), 256, 0, stream>>>(Ob, woT, d_out);
}

// Round 4
// 528.576 us; speedup vs baseline: 21.6606x; 1.0768x over previous
//
#include <hip/hip_runtime.h>
#include <cstdint>
#include <cstddef>

#define DIM 2048
#define NHEADS 16
#define HD 128
#define BATCH 4
#define SEQ 2048
#define MROWS (BATCH*SEQ)   // 8192

typedef __attribute__((ext_vector_type(4))) float  f32x4;
typedef __attribute__((ext_vector_type(4))) float  float4v;
typedef __attribute__((ext_vector_type(8))) short  short8;
typedef __attribute__((ext_vector_type(4))) short  short4v;
typedef __attribute__((ext_vector_type(4))) unsigned uint4v;
typedef __attribute__((ext_vector_type(8))) __bf16 bf16x8;

// Q is pre-scaled by (1/sqrt(128)) * log2(e) so flash softmax runs in exp2 domain.
#define QSCALE 0.1275173772f

__device__ __forceinline__ unsigned f2bfbits(float f) {
  unsigned u = __builtin_bit_cast(unsigned, f);
  return (u + 0x7FFFu + ((u >> 16) & 1u)) >> 16;
}
__device__ __forceinline__ short f2bf(float f) { return (short)f2bfbits(f); }
__device__ __forceinline__ float bf2f(short s) {
  unsigned u = ((unsigned)(unsigned short)s) << 16;
  return __builtin_bit_cast(float, u);
}
__device__ __forceinline__ unsigned cvtpk_bf16(float lo, float hi) {
  unsigned r;
  asm("v_cvt_pk_bf16_f32 %0, %1, %2" : "=v"(r) : "v"(lo), "v"(hi));
  return r;
}
__device__ __forceinline__ f32x4 mfma16(short8 a, short8 b, f32x4 c) {
  return __builtin_amdgcn_mfma_f32_16x16x32_bf16(
      __builtin_bit_cast(bf16x8, a), __builtin_bit_cast(bf16x8, b), c, 0, 0, 0);
}

// ---------------------------------------------------------------- prep: x -> bf16
__global__ __launch_bounds__(256) void k_convert_x(const float* __restrict__ x,
                                                   short* __restrict__ xb) {
  size_t i = ((size_t)blockIdx.x * 256 + threadIdx.x) * 8;
  float4v a = *(const float4v*)(x + i);
  float4v b = *(const float4v*)(x + i + 4);
  short8 o;
  o[0] = f2bf(a[0]); o[1] = f2bf(a[1]); o[2] = f2bf(a[2]); o[3] = f2bf(a[3]);
  o[4] = f2bf(b[0]); o[5] = f2bf(b[1]); o[6] = f2bf(b[2]); o[7] = f2bf(b[3]);
  *(short8*)(xb + i) = o;
}

// ------------------------------------------------- prep: W [K][N] f32 -> Wt [N][K] bf16
__global__ __launch_bounds__(256) void k_transpose_w(
    const float* __restrict__ w0, const float* __restrict__ w1,
    const float* __restrict__ w2, const float* __restrict__ w3,
    short* __restrict__ o0, short* __restrict__ o1,
    short* __restrict__ o2, short* __restrict__ o3) {
  const float* w; short* o;
  switch (blockIdx.z) {
    case 0: w = w0; o = o0; break;
    case 1: w = w1; o = o1; break;
    case 2: w = w2; o = o2; break;
    default: w = w3; o = o3; break;
  }
  __shared__ float tile[32][33];
  int tx = threadIdx.x, ty = threadIdx.y;          // 32 x 8
  int kb = blockIdx.y * 32, nb = blockIdx.x * 32;
#pragma unroll
  for (int i = 0; i < 4; ++i)
    tile[ty + 8 * i][tx] = w[(size_t)(kb + ty + 8 * i) * DIM + nb + tx];
  __syncthreads();
#pragma unroll
  for (int i = 0; i < 4; ++i)
    o[(size_t)(nb + ty + 8 * i) * DIM + kb + tx] = f2bf(tile[tx][ty + 8 * i]);
}

// ---------------------------------------------------------------- fused QKV GEMM + RoPE
// C[M=8192][6144] = xb[M][K=2048] @ [wqT|wkT|wvT]^T, per 128x128 block.
// blockIdx.x: 0..47 -> which = x>>4 (0=Q,1=K,2=V), n0 = (x&15)*128 (= head h, cols d 0..127).
// Wave cols remapped so the RoPE pair (d, d+64) is in-wave: ncol(j) = (j&1)*16 + (j>>1)*64 + wn*32.
// Q/K: rope applied on f32 acc (Q also * QSCALE), stored bf16 (B,H,S,D).
// V: stored bf16 transposed (B,H,D,S).
__global__ __launch_bounds__(256) void k_gemm_qkv(const short* __restrict__ A,
                                                  const short* __restrict__ BtAll,
                                                  const float* __restrict__ cosg,
                                                  const float* __restrict__ sing,
                                                  short* __restrict__ Qp,
                                                  short* __restrict__ Kp,
                                                  short* __restrict__ Vp) {
  __shared__ short As[128][72];
  __shared__ short Bs[128][72];
  const int t = threadIdx.x;
  const int lane = t & 63, wid = t >> 6;
  const int wm = wid >> 1, wn = wid & 1;
  const int gi = lane >> 4, li = lane & 15;
  const int bx = blockIdx.x;
  const int which = bx >> 4;
  const int n0 = (bx & 15) * 128;
  const int m0 = blockIdx.y * 128;
  const short* Bt = BtAll + (size_t)which * DIM * DIM;

  f32x4 acc[4][4];
#pragma unroll
  for (int i = 0; i < 4; ++i)
#pragma unroll
    for (int j = 0; j < 4; ++j) acc[i][j] = (f32x4){0.f, 0.f, 0.f, 0.f};

  for (int k0 = 0; k0 < DIM; k0 += 64) {
#pragma unroll
    for (int i = 0; i < 4; ++i) {
      int idx = i * 256 + t;
      int r = idx >> 3, c = (idx & 7) * 8;
      *(short8*)&As[r][c] = *(const short8*)(A + (size_t)(m0 + r) * DIM + k0 + c);
      *(short8*)&Bs[r][c] = *(const short8*)(Bt + (size_t)(n0 + r) * DIM + k0 + c);
    }
    __syncthreads();
#pragma unroll
    for (int kk = 0; kk < 2; ++kk) {
      short8 av[4], bv[4];
#pragma unroll
      for (int i = 0; i < 4; ++i) {
        int ncol = (i & 1) * 16 + (i >> 1) * 64 + wn * 32;
        av[i] = *(const short8*)&As[64 * wm + 16 * i + li][kk * 32 + 8 * gi];
        bv[i] = *(const short8*)&Bs[ncol + li][kk * 32 + 8 * gi];
      }
#pragma unroll
      for (int i = 0; i < 4; ++i)
#pragma unroll
        for (int j = 0; j < 4; ++j)
          acc[i][j] = mfma16(av[i], bv[j], acc[i][j]);
    }
    __syncthreads();
  }

  const int h = n0 >> 7;
  if (which == 2) {                               // V -> (B,H,D,S)
#pragma unroll
    for (int i = 0; i < 4; ++i)
#pragma unroll
      for (int j = 0; j < 4; ++j) {
        int gm0 = m0 + 64 * wm + 16 * i + 4 * gi;
        int b = gm0 >> 11, s0 = gm0 & 2047;
        int d = (j & 1) * 16 + (j >> 1) * 64 + wn * 32 + li;
        short4v pk;
#pragma unroll
        for (int r = 0; r < 4; ++r) pk[r] = f2bf(acc[i][j][r]);
        *(short4v*)&Vp[((size_t)(b * NHEADS + h) * HD + d) * SEQ + s0] = pk;
      }
  } else {                                        // Q or K: rope + store (B,H,S,D)
    short* O = which ? Kp : Qp;
    const float qs = which ? 1.0f : QSCALE;
#pragma unroll
    for (int i = 0; i < 4; ++i)
#pragma unroll
      for (int j = 0; j < 2; ++j) {
        int dlo = j * 16 + wn * 32 + li;          // in [0,64)
#pragma unroll
        for (int r = 0; r < 4; ++r) {
          int gm = m0 + 64 * wm + 16 * i + 4 * gi + r;
          int b = gm >> 11, s = gm & 2047;
          float c = cosg[s * 64 + dlo], sn = sing[s * 64 + dlo];
          float a = acc[i][j][r], bb = acc[i][j + 2][r];
          size_t base = ((size_t)(b * NHEADS + h) * SEQ + s) * HD;
          O[base + dlo]      = f2bf((a * c - bb * sn) * qs);
          O[base + dlo + 64] = f2bf((bb * c + a * sn) * qs);
        }
      }
  }
}

// ---------------------------------------------------------------- GEMM (final projection)
// C[M][N=2048] f32 = A[M][K] bf16 @ Bt[N][K]^T
__global__ __launch_bounds__(256) void k_gemm_out(const short* __restrict__ A,
                                                  const short* __restrict__ Bt,
                                                  float* __restrict__ O) {
  __shared__ short As[128][72];
  __shared__ short Bs[128][72];
  const int t = threadIdx.x;
  const int lane = t & 63, wid = t >> 6;
  const int wm = wid >> 1, wn = wid & 1;
  const int gi = lane >> 4, li = lane & 15;
  const int m0 = blockIdx.y * 128, n0 = blockIdx.x * 128;

  f32x4 acc[4][4];
#pragma unroll
  for (int i = 0; i < 4; ++i)
#pragma unroll
    for (int j = 0; j < 4; ++j) acc[i][j] = (f32x4){0.f, 0.f, 0.f, 0.f};

  for (int k0 = 0; k0 < DIM; k0 += 64) {
#pragma unroll
    for (int i = 0; i < 4; ++i) {
      int idx = i * 256 + t;
      int r = idx >> 3, c = (idx & 7) * 8;
      *(short8*)&As[r][c] = *(const short8*)(A + (size_t)(m0 + r) * DIM + k0 + c);
      *(short8*)&Bs[r][c] = *(const short8*)(Bt + (size_t)(n0 + r) * DIM + k0 + c);
    }
    __syncthreads();
#pragma unroll
    for (int kk = 0; kk < 2; ++kk) {
      short8 av[4], bv[4];
#pragma unroll
      for (int i = 0; i < 4; ++i) {
        av[i] = *(const short8*)&As[64 * wm + 16 * i + li][kk * 32 + 8 * gi];
        bv[i] = *(const short8*)&Bs[64 * wn + 16 * i + li][kk * 32 + 8 * gi];
      }
#pragma unroll
      for (int i = 0; i < 4; ++i)
#pragma unroll
        for (int j = 0; j < 4; ++j)
          acc[i][j] = mfma16(av[i], bv[j], acc[i][j]);
    }
    __syncthreads();
  }

#pragma unroll
  for (int i = 0; i < 4; ++i)
#pragma unroll
    for (int j = 0; j < 4; ++j)
#pragma unroll
      for (int r = 0; r < 4; ++r) {
        int gm = m0 + 64 * wm + 16 * i + 4 * gi + r;
        int gn = n0 + 64 * wn + 16 * j + li;
        O[(size_t)gm * DIM + gn] = acc[i][j][r];
      }
}

// ---------------------------------------------------------------- causal flash attention
// Q (pre-scaled by QSCALE, roped), K (roped): (B,H,S,D) bf16; V: (B,H,D,S) bf16.
// LPT dispatch: grid 2048, ip = 31 - id/64 (heavy first), bh = id & 63.
// exp2-domain online softmax + defer-max (THR = 11.54 = 8*log2e) + cvt_pk bf16 packing.
__global__ __launch_bounds__(256) void k_flash(const short* __restrict__ Qg,
                                               const short* __restrict__ Kg,
                                               const short* __restrict__ Vg,
                                               short* __restrict__ Og) {
  __shared__ short Ks[64][136];
  __shared__ short Vs[128][72];
  const int t = threadIdx.x, lane = t & 63, wid = t >> 6;
  const int gi = lane >> 4, li = lane & 15;
  const int id = blockIdx.x;
  const int ip = 31 - (id >> 6);                  // q-tile index, heavy-first
  const int bh = id & 63;
  const int q0 = ip * 64;
  const short* Qb = Qg + (size_t)bh * SEQ * HD;
  const short* Kb = Kg + (size_t)bh * SEQ * HD;
  const short* Vb = Vg + (size_t)bh * HD * SEQ;
  const int mrow = q0 + wid * 16 + li;            // this lane's q row

  short8 qb[4];
#pragma unroll
  for (int kk = 0; kk < 4; ++kk)
    qb[kk] = *(const short8*)(Qb + (size_t)mrow * HD + kk * 32 + 8 * gi);

  f32x4 o[8];
#pragma unroll
  for (int d = 0; d < 8; ++d) o[d] = (f32x4){0.f, 0.f, 0.f, 0.f};
  float mx = -1e30f, lsum = 0.f;
  const int nt = ip + 1;
  const int srcA = li | ((lane & 16) << 1);       // (m, 2*(g&1))
  const int srcB = srcA + 16;
  const bool hig = (lane & 32) != 0;

  for (int tt = 0; tt < nt; ++tt) {
    const int k0 = tt * 64;
#pragma unroll
    for (int i = 0; i < 4; ++i) {
      int idx = i * 256 + t;
      { int r = idx >> 4, c = (idx & 15) * 8;
        *(short8*)&Ks[r][c] = *(const short8*)(Kb + (size_t)(k0 + r) * HD + c); }
      { int r = idx >> 3, c = (idx & 7) * 8;
        *(short8*)&Vs[r][c] = *(const short8*)(Vb + (size_t)r * SEQ + k0 + c); }
    }
    __syncthreads();

    f32x4 sacc[4];
#pragma unroll
    for (int af = 0; af < 4; ++af) sacc[af] = (f32x4){0.f, 0.f, 0.f, 0.f};
    __builtin_amdgcn_s_setprio(1);
#pragma unroll
    for (int kk = 0; kk < 4; ++kk)
#pragma unroll
      for (int af = 0; af < 4; ++af) {
        short8 kf = *(const short8*)&Ks[16 * af + li][kk * 32 + 8 * gi];
        sacc[af] = mfma16(kf, qb[kk], sacc[af]);
      }
    __builtin_amdgcn_s_setprio(0);

    float p[4][4];
    float pmax = -1e30f;
    const bool last = (tt == nt - 1);
#pragma unroll
    for (int af = 0; af < 4; ++af)
#pragma unroll
      for (int r = 0; r < 4; ++r) {
        float v = sacc[af][r];                    // already scaled (Q pre-scale)
        if (last && (k0 + 16 * af + 4 * gi + r > mrow)) v = -1e30f;
        p[af][r] = v;
        pmax = fmaxf(pmax, v);
      }
    pmax = fmaxf(pmax, __shfl_xor(pmax, 16));
    pmax = fmaxf(pmax, __shfl_xor(pmax, 32));
    if (!__all(pmax <= mx + 11.54f)) {            // defer-max: rescale only on real growth
      float mnew = fmaxf(mx, pmax);
      float alpha = __builtin_amdgcn_exp2f(mx - mnew);
      lsum *= alpha;
      mx = mnew;
#pragma unroll
      for (int d = 0; d < 8; ++d) o[d] *= alpha;
    }
    float psum = 0.f;
#pragma unroll
    for (int af = 0; af < 4; ++af)
#pragma unroll
      for (int r = 0; r < 4; ++r) {
        float e = __builtin_amdgcn_exp2f(p[af][r] - mx);
        p[af][r] = e;
        psum += e;
      }
    psum += __shfl_xor(psum, 16);
    psum += __shfl_xor(psum, 32);
    lsum += psum;

    unsigned plo[4], phi[4];
#pragma unroll
    for (int af = 0; af < 4; ++af) {
      plo[af] = cvtpk_bf16(p[af][0], p[af][1]);
      phi[af] = cvtpk_bf16(p[af][2], p[af][3]);
    }
#pragma unroll
    for (int kk2 = 0; kk2 < 2; ++kk2) {
      unsigned aAlo = (unsigned)__shfl((int)plo[2 * kk2], srcA);
      unsigned aAhi = (unsigned)__shfl((int)phi[2 * kk2], srcA);
      unsigned aBlo = (unsigned)__shfl((int)plo[2 * kk2 + 1], srcA);
      unsigned aBhi = (unsigned)__shfl((int)phi[2 * kk2 + 1], srcA);
      unsigned bAlo = (unsigned)__shfl((int)plo[2 * kk2], srcB);
      unsigned bAhi = (unsigned)__shfl((int)phi[2 * kk2], srcB);
      unsigned bBlo = (unsigned)__shfl((int)plo[2 * kk2 + 1], srcB);
      unsigned bBhi = (unsigned)__shfl((int)phi[2 * kk2 + 1], srcB);
      uint4v dws;
      dws[0] = hig ? aBlo : aAlo;
      dws[1] = hig ? aBhi : aAhi;
      dws[2] = hig ? bBlo : bAlo;
      dws[3] = hig ? bBhi : bAhi;
      short8 pbf = __builtin_bit_cast(short8, dws);
      __builtin_amdgcn_s_setprio(1);
#pragma unroll
      for (int d = 0; d < 8; ++d) {
        short8 vf = *(const short8*)&Vs[16 * d + li][kk2 * 32 + 8 * gi];
        o[d] = mfma16(vf, pbf, o[d]);
      }
      __builtin_amdgcn_s_setprio(0);
    }
    __syncthreads();
  }

  const float inv = 1.0f / lsum;
  const int b = bh >> 4, h = bh & 15;
  const size_t obase = ((size_t)b * SEQ + mrow) * DIM + h * HD;
#pragma unroll
  for (int d = 0; d < 8; ++d) {
    short4v st;
#pragma unroll
    for (int r = 0; r < 4; ++r) st[r] = f2bf(o[d][r] * inv);
    *(short4v*)&Og[obase + d * 16 + 4 * gi] = st;
  }
}

// ---------------------------------------------------------------- launcher
extern "C" void kernel_launch(void* const* d_in, const int* in_sizes, int n_in,
                              void* d_out, int out_size, void* d_ws, size_t ws_size,
                              hipStream_t stream) {
  (void)in_sizes; (void)n_in; (void)out_size;
  const float* x    = (const float*)d_in[0];
  const float* cosg = (const float*)d_in[1];
  const float* sing = (const float*)d_in[2];
  const float* wq   = (const float*)d_in[3];
  const float* wk   = (const float*)d_in[4];
  const float* wv   = (const float*)d_in[5];
  const float* wo   = (const float*)d_in[6];

  const size_t SZ = (size_t)MROWS * DIM * 2;      // 33,554,432 B
  char* ws = (char*)d_ws;
  short* xb  = (short*)ws;                        // region 0, later reused as attn-out O
  short* wqT = (short*)(ws + SZ);                 // wqT|wkT|wvT contiguous (BtAll)
  short* wkT = wqT + (size_t)DIM * DIM;
  short* wvT = wkT + (size_t)DIM * DIM;
  short* woT = wvT + (size_t)DIM * DIM;
  short *Qp, *Kp, *Vp;
  if (ws_size >= 5 * SZ) {
    Qp = (short*)(ws + 2 * SZ);
    Kp = (short*)(ws + 3 * SZ);
    Vp = (short*)(ws + 4 * SZ);
  } else {                                        // park Q,K in d_out (overwritten at the end)
    Qp = (short*)d_out;
    Kp = (short*)d_out + SZ / 2;
    Vp = (short*)(ws + 2 * SZ);
  }
  short* Ob = xb;                                 // alias: xb dead after QKV GEMM

  k_convert_x<<<8192, 256, 0, stream>>>(x, xb);
  k_transpose_w<<<dim3(64, 64, 4), dim3(32, 8), 0, stream>>>(wq, wk, wv, wo,
                                                             wqT, wkT, wvT, woT);
  k_gemm_qkv<<<dim3(48, 64), 256, 0, stream>>>(xb, wqT, cosg, sing, Qp, Kp, Vp);
  k_flash<<<2048, 256, 0, stream>>>(Qp, Kp, Vp, Ob);
  k_gemm_out<<<dim3(16, 64), 256, 0, stream>>>(Ob, woT, (float*)d_out);
}

// Round 5
// 524.333 us; speedup vs baseline: 21.8359x; 1.0081x over previous
//
#include <hip/hip_runtime.h>
#include <cstdint>
#include <cstddef>

#define DIM 2048
#define NHEADS 16
#define HD 128
#define BATCH 4
#define SEQ 2048
#define MROWS (BATCH*SEQ)   // 8192

typedef __attribute__((ext_vector_type(4))) float  f32x4;
typedef __attribute__((ext_vector_type(4))) float  float4v;
typedef __attribute__((ext_vector_type(8))) short  short8;
typedef __attribute__((ext_vector_type(4))) short  short4v;
typedef __attribute__((ext_vector_type(4))) unsigned uint4v;
typedef __attribute__((ext_vector_type(8))) __bf16 bf16x8;

// Q is pre-scaled by (1/sqrt(128)) * log2(e) so flash softmax runs in exp2 domain.
#define QSCALE 0.1275173772f

__device__ __forceinline__ unsigned f2bfbits(float f) {
  unsigned u = __builtin_bit_cast(unsigned, f);
  return (u + 0x7FFFu + ((u >> 16) & 1u)) >> 16;
}
__device__ __forceinline__ short f2bf(float f) { return (short)f2bfbits(f); }
__device__ __forceinline__ float bf2f(short s) {
  unsigned u = ((unsigned)(unsigned short)s) << 16;
  return __builtin_bit_cast(float, u);
}
__device__ __forceinline__ unsigned cvtpk_bf16(float lo, float hi) {
  unsigned r;
  asm("v_cvt_pk_bf16_f32 %0, %1, %2" : "=v"(r) : "v"(lo), "v"(hi));
  return r;
}
__device__ __forceinline__ f32x4 mfma16(short8 a, short8 b, f32x4 c) {
  return __builtin_amdgcn_mfma_f32_16x16x32_bf16(
      __builtin_bit_cast(bf16x8, a), __builtin_bit_cast(bf16x8, b), c, 0, 0, 0);
}
// async global->LDS, 16B per lane. LDS dest is wave-uniform base + lane*16.
__device__ __forceinline__ void gload16(const short* g, short* l) {
  __builtin_amdgcn_global_load_lds(
      (const __attribute__((address_space(1))) unsigned int*)g,
      (__attribute__((address_space(3))) unsigned int*)l, 16, 0, 0);
}

// ---------------------------------------------------------------- prep: x -> bf16
__global__ __launch_bounds__(256) void k_convert_x(const float* __restrict__ x,
                                                   short* __restrict__ xb) {
  size_t i = ((size_t)blockIdx.x * 256 + threadIdx.x) * 8;
  float4v a = *(const float4v*)(x + i);
  float4v b = *(const float4v*)(x + i + 4);
  short8 o;
  o[0] = f2bf(a[0]); o[1] = f2bf(a[1]); o[2] = f2bf(a[2]); o[3] = f2bf(a[3]);
  o[4] = f2bf(b[0]); o[5] = f2bf(b[1]); o[6] = f2bf(b[2]); o[7] = f2bf(b[3]);
  *(short8*)(xb + i) = o;
}

// ------------------------------------------------- prep: W [K][N] f32 -> Wt [N][K] bf16
__global__ __launch_bounds__(256) void k_transpose_w(
    const float* __restrict__ w0, const float* __restrict__ w1,
    const float* __restrict__ w2, const float* __restrict__ w3,
    short* __restrict__ o0, short* __restrict__ o1,
    short* __restrict__ o2, short* __restrict__ o3) {
  const float* w; short* o;
  switch (blockIdx.z) {
    case 0: w = w0; o = o0; break;
    case 1: w = w1; o = o1; break;
    case 2: w = w2; o = o2; break;
    default: w = w3; o = o3; break;
  }
  __shared__ float tile[32][33];
  int tx = threadIdx.x, ty = threadIdx.y;          // 32 x 8
  int kb = blockIdx.y * 32, nb = blockIdx.x * 32;
#pragma unroll
  for (int i = 0; i < 4; ++i)
    tile[ty + 8 * i][tx] = w[(size_t)(kb + ty + 8 * i) * DIM + nb + tx];
  __syncthreads();
#pragma unroll
  for (int i = 0; i < 4; ++i)
    o[(size_t)(nb + ty + 8 * i) * DIM + kb + tx] = f2bf(tile[tx][ty + 8 * i]);
}

// ---------------------------------------------------------------- fused QKV GEMM + RoPE
// Staging via global_load_lds(16B) into LINEAR LDS [128][64] shorts; the fragment
// read pattern is bank-balanced via an XOR swizzle applied BOTH sides:
//   stage:  lane l of wave-load covering rows 8b..8b+7 reads global col-byte
//           ((l&7)^(l>>3))*16 of row 8b+(l>>3)  ->  LDS[r][cb] = G[r][cb ^ ((r&7)<<4)]
//   read:   fragment slot (4kk+gi) read at slot ^ (li&7)   (same involution)
// Grid: flat 3072 with bijective XCD remap (nwg%8==0): wg=(id&7)*384+(id>>3).
__global__ __launch_bounds__(256) void k_gemm_qkv(const short* __restrict__ A,
                                                  const short* __restrict__ BtAll,
                                                  const float* __restrict__ cosg,
                                                  const float* __restrict__ sing,
                                                  short* __restrict__ Qp,
                                                  short* __restrict__ Kp,
                                                  short* __restrict__ Vp) {
  __shared__ short As[128 * 64];
  __shared__ short Bs[128 * 64];
  const int t = threadIdx.x;
  const int lane = t & 63, wid = t >> 6;
  const int wm = wid >> 1, wn = wid & 1;
  const int gi = lane >> 4, li = lane & 15;
  const int id = blockIdx.x;
  const int wg = (id & 7) * 384 + (id >> 3);      // XCD-contiguous chunks
  const int my = wg / 48, bx = wg % 48;
  const int which = bx >> 4;
  const int n0 = (bx & 15) * 128;
  const int m0 = my * 128;
  const short* Bt = BtAll + (size_t)which * DIM * DIM;

  const int lrow = lane >> 3;                     // 0..7
  const int lcol = ((lane & 7) ^ lrow) * 8;       // pre-swizzled source col (shorts)

  f32x4 acc[4][4];
#pragma unroll
  for (int i = 0; i < 4; ++i)
#pragma unroll
    for (int j = 0; j < 4; ++j) acc[i][j] = (f32x4){0.f, 0.f, 0.f, 0.f};

  for (int k0 = 0; k0 < DIM; k0 += 64) {
#pragma unroll
    for (int i = 0; i < 4; ++i) {
      int blk = wid * 4 + i;                      // 0..15, covers rows 8*blk..8*blk+7
      int r = blk * 8 + lrow;
      gload16(A + (size_t)(m0 + r) * DIM + k0 + lcol, &As[blk * 512]);
      gload16(Bt + (size_t)(n0 + r) * DIM + k0 + lcol, &Bs[blk * 512]);
    }
    __syncthreads();
#pragma unroll
    for (int kk = 0; kk < 2; ++kk) {
      short8 av[4], bv[4];
      const int sw = (((kk << 2) | gi) ^ (li & 7)) * 8;
#pragma unroll
      for (int i = 0; i < 4; ++i) {
        int ncol = (i & 1) * 16 + (i >> 1) * 64 + wn * 32;
        av[i] = *(const short8*)&As[(64 * wm + 16 * i + li) * 64 + sw];
        bv[i] = *(const short8*)&Bs[(ncol + li) * 64 + sw];
      }
#pragma unroll
      for (int i = 0; i < 4; ++i)
#pragma unroll
        for (int j = 0; j < 4; ++j)
          acc[i][j] = mfma16(av[i], bv[j], acc[i][j]);
    }
    __syncthreads();
  }

  const int h = n0 >> 7;
  if (which == 2) {                               // V -> (B,H,D,S)
#pragma unroll
    for (int i = 0; i < 4; ++i)
#pragma unroll
      for (int j = 0; j < 4; ++j) {
        int gm0 = m0 + 64 * wm + 16 * i + 4 * gi;
        int b = gm0 >> 11, s0 = gm0 & 2047;
        int d = (j & 1) * 16 + (j >> 1) * 64 + wn * 32 + li;
        short4v pk;
#pragma unroll
        for (int r = 0; r < 4; ++r) pk[r] = f2bf(acc[i][j][r]);
        *(short4v*)&Vp[((size_t)(b * NHEADS + h) * HD + d) * SEQ + s0] = pk;
      }
  } else {                                        // Q or K: rope + store (B,H,S,D)
    short* O = which ? Kp : Qp;
    const float qs = which ? 1.0f : QSCALE;
#pragma unroll
    for (int i = 0; i < 4; ++i)
#pragma unroll
      for (int j = 0; j < 2; ++j) {
        int dlo = j * 16 + wn * 32 + li;          // in [0,64)
#pragma unroll
        for (int r = 0; r < 4; ++r) {
          int gm = m0 + 64 * wm + 16 * i + 4 * gi + r;
          int b = gm >> 11, s = gm & 2047;
          float c = cosg[s * 64 + dlo], sn = sing[s * 64 + dlo];
          float a = acc[i][j][r], bb = acc[i][j + 2][r];
          size_t base = ((size_t)(b * NHEADS + h) * SEQ + s) * HD;
          O[base + dlo]      = f2bf((a * c - bb * sn) * qs);
          O[base + dlo + 64] = f2bf((bb * c + a * sn) * qs);
        }
      }
  }
}

// ---------------------------------------------------------------- GEMM (final projection)
// Same gload_lds + swizzle staging. Grid flat 1024, XCD remap wg=(id&7)*128+(id>>3).
__global__ __launch_bounds__(256) void k_gemm_out(const short* __restrict__ A,
                                                  const short* __restrict__ Bt,
                                                  float* __restrict__ O) {
  __shared__ short As[128 * 64];
  __shared__ short Bs[128 * 64];
  const int t = threadIdx.x;
  const int lane = t & 63, wid = t >> 6;
  const int wm = wid >> 1, wn = wid & 1;
  const int gi = lane >> 4, li = lane & 15;
  const int id = blockIdx.x;
  const int wg = (id & 7) * 128 + (id >> 3);
  const int m0 = (wg >> 4) * 128, n0 = (wg & 15) * 128;

  const int lrow = lane >> 3;
  const int lcol = ((lane & 7) ^ lrow) * 8;

  f32x4 acc[4][4];
#pragma unroll
  for (int i = 0; i < 4; ++i)
#pragma unroll
    for (int j = 0; j < 4; ++j) acc[i][j] = (f32x4){0.f, 0.f, 0.f, 0.f};

  for (int k0 = 0; k0 < DIM; k0 += 64) {
#pragma unroll
    for (int i = 0; i < 4; ++i) {
      int blk = wid * 4 + i;
      int r = blk * 8 + lrow;
      gload16(A + (size_t)(m0 + r) * DIM + k0 + lcol, &As[blk * 512]);
      gload16(Bt + (size_t)(n0 + r) * DIM + k0 + lcol, &Bs[blk * 512]);
    }
    __syncthreads();
#pragma unroll
    for (int kk = 0; kk < 2; ++kk) {
      short8 av[4], bv[4];
      const int sw = (((kk << 2) | gi) ^ (li & 7)) * 8;
#pragma unroll
      for (int i = 0; i < 4; ++i) {
        av[i] = *(const short8*)&As[(64 * wm + 16 * i + li) * 64 + sw];
        bv[i] = *(const short8*)&Bs[(64 * wn + 16 * i + li) * 64 + sw];
      }
#pragma unroll
      for (int i = 0; i < 4; ++i)
#pragma unroll
        for (int j = 0; j < 4; ++j)
          acc[i][j] = mfma16(av[i], bv[j], acc[i][j]);
    }
    __syncthreads();
  }

#pragma unroll
  for (int i = 0; i < 4; ++i)
#pragma unroll
    for (int j = 0; j < 4; ++j)
#pragma unroll
      for (int r = 0; r < 4; ++r) {
        int gm = m0 + 64 * wm + 16 * i + 4 * gi + r;
        int gn = n0 + 64 * wn + 16 * j + li;
        O[(size_t)gm * DIM + gn] = acc[i][j][r];
      }
}

// ---------------------------------------------------------------- causal flash attention
// Q (pre-scaled by QSCALE, roped), K (roped): (B,H,S,D) bf16; V: (B,H,D,S) bf16.
// LPT dispatch: grid 2048, ip = 31 - id/64 (heavy first), bh = id & 63.
// exp2-domain online softmax + defer-max (THR = 11.54 = 8*log2e) + cvt_pk bf16 packing.
__global__ __launch_bounds__(256) void k_flash(const short* __restrict__ Qg,
                                               const short* __restrict__ Kg,
                                               const short* __restrict__ Vg,
                                               short* __restrict__ Og) {
  __shared__ short Ks[64][136];
  __shared__ short Vs[128][72];
  const int t = threadIdx.x, lane = t & 63, wid = t >> 6;
  const int gi = lane >> 4, li = lane & 15;
  const int id = blockIdx.x;
  const int ip = 31 - (id >> 6);                  // q-tile index, heavy-first
  const int bh = id & 63;
  const int q0 = ip * 64;
  const short* Qb = Qg + (size_t)bh * SEQ * HD;
  const short* Kb = Kg + (size_t)bh * SEQ * HD;
  const short* Vb = Vg + (size_t)bh * HD * SEQ;
  const int mrow = q0 + wid * 16 + li;            // this lane's q row

  short8 qb[4];
#pragma unroll
  for (int kk = 0; kk < 4; ++kk)
    qb[kk] = *(const short8*)(Qb + (size_t)mrow * HD + kk * 32 + 8 * gi);

  f32x4 o[8];
#pragma unroll
  for (int d = 0; d < 8; ++d) o[d] = (f32x4){0.f, 0.f, 0.f, 0.f};
  float mx = -1e30f, lsum = 0.f;
  const int nt = ip + 1;
  const int srcA = li | ((lane & 16) << 1);       // (m, 2*(g&1))
  const int srcB = srcA + 16;
  const bool hig = (lane & 32) != 0;

  for (int tt = 0; tt < nt; ++tt) {
    const int k0 = tt * 64;
#pragma unroll
    for (int i = 0; i < 4; ++i) {
      int idx = i * 256 + t;
      { int r = idx >> 4, c = (idx & 15) * 8;
        *(short8*)&Ks[r][c] = *(const short8*)(Kb + (size_t)(k0 + r) * HD + c); }
      { int r = idx >> 3, c = (idx & 7) * 8;
        *(short8*)&Vs[r][c] = *(const short8*)(Vb + (size_t)r * SEQ + k0 + c); }
    }
    __syncthreads();

    f32x4 sacc[4];
#pragma unroll
    for (int af = 0; af < 4; ++af) sacc[af] = (f32x4){0.f, 0.f, 0.f, 0.f};
    __builtin_amdgcn_s_setprio(1);
#pragma unroll
    for (int kk = 0; kk < 4; ++kk)
#pragma unroll
      for (int af = 0; af < 4; ++af) {
        short8 kf = *(const short8*)&Ks[16 * af + li][kk * 32 + 8 * gi];
        sacc[af] = mfma16(kf, qb[kk], sacc[af]);
      }
    __builtin_amdgcn_s_setprio(0);

    float p[4][4];
    float pmax = -1e30f;
    const bool last = (tt == nt - 1);
#pragma unroll
    for (int af = 0; af < 4; ++af)
#pragma unroll
      for (int r = 0; r < 4; ++r) {
        float v = sacc[af][r];                    // already scaled (Q pre-scale)
        if (last && (k0 + 16 * af + 4 * gi + r > mrow)) v = -1e30f;
        p[af][r] = v;
        pmax = fmaxf(pmax, v);
      }
    pmax = fmaxf(pmax, __shfl_xor(pmax, 16));
    pmax = fmaxf(pmax, __shfl_xor(pmax, 32));
    if (!__all(pmax <= mx + 11.54f)) {            // defer-max: rescale only on real growth
      float mnew = fmaxf(mx, pmax);
      float alpha = __builtin_amdgcn_exp2f(mx - mnew);
      lsum *= alpha;
      mx = mnew;
#pragma unroll
      for (int d = 0; d < 8; ++d) o[d] *= alpha;
    }
    float psum = 0.f;
#pragma unroll
    for (int af = 0; af < 4; ++af)
#pragma unroll
      for (int r = 0; r < 4; ++r) {
        float e = __builtin_amdgcn_exp2f(p[af][r] - mx);
        p[af][r] = e;
        psum += e;
      }
    psum += __shfl_xor(psum, 16);
    psum += __shfl_xor(psum, 32);
    lsum += psum;

    unsigned plo[4], phi[4];
#pragma unroll
    for (int af = 0; af < 4; ++af) {
      plo[af] = cvtpk_bf16(p[af][0], p[af][1]);
      phi[af] = cvtpk_bf16(p[af][2], p[af][3]);
    }
#pragma unroll
    for (int kk2 = 0; kk2 < 2; ++kk2) {
      unsigned aAlo = (unsigned)__shfl((int)plo[2 * kk2], srcA);
      unsigned aAhi = (unsigned)__shfl((int)phi[2 * kk2], srcA);
      unsigned aBlo = (unsigned)__shfl((int)plo[2 * kk2 + 1], srcA);
      unsigned aBhi = (unsigned)__shfl((int)phi[2 * kk2 + 1], srcA);
      unsigned bAlo = (unsigned)__shfl((int)plo[2 * kk2], srcB);
      unsigned bAhi = (unsigned)__shfl((int)phi[2 * kk2], srcB);
      unsigned bBlo = (unsigned)__shfl((int)plo[2 * kk2 + 1], srcB);
      unsigned bBhi = (unsigned)__shfl((int)phi[2 * kk2 + 1], srcB);
      uint4v dws;
      dws[0] = hig ? aBlo : aAlo;
      dws[1] = hig ? aBhi : aAhi;
      dws[2] = hig ? bBlo : bAlo;
      dws[3] = hig ? bBhi : bAhi;
      short8 pbf = __builtin_bit_cast(short8, dws);
      __builtin_amdgcn_s_setprio(1);
#pragma unroll
      for (int d = 0; d < 8; ++d) {
        short8 vf = *(const short8*)&Vs[16 * d + li][kk2 * 32 + 8 * gi];
        o[d] = mfma16(vf, pbf, o[d]);
      }
      __builtin_amdgcn_s_setprio(0);
    }
    __syncthreads();
  }

  const float inv = 1.0f / lsum;
  const int b = bh >> 4, h = bh & 15;
  const size_t obase = ((size_t)b * SEQ + mrow) * DIM + h * HD;
#pragma unroll
  for (int d = 0; d < 8; ++d) {
    short4v st;
#pragma unroll
    for (int r = 0; r < 4; ++r) st[r] = f2bf(o[d][r] * inv);
    *(short4v*)&Og[obase + d * 16 + 4 * gi] = st;
  }
}

// ---------------------------------------------------------------- launcher
extern "C" void kernel_launch(void* const* d_in, const int* in_sizes, int n_in,
                              void* d_out, int out_size, void* d_ws, size_t ws_size,
                              hipStream_t stream) {
  (void)in_sizes; (void)n_in; (void)out_size;
  const float* x    = (const float*)d_in[0];
  const float* cosg = (const float*)d_in[1];
  const float* sing = (const float*)d_in[2];
  const float* wq   = (const float*)d_in[3];
  const float* wk   = (const float*)d_in[4];
  const float* wv   = (const float*)d_in[5];
  const float* wo   = (const float*)d_in[6];

  const size_t SZ = (size_t)MROWS * DIM * 2;      // 33,554,432 B
  char* ws = (char*)d_ws;
  short* xb  = (short*)ws;                        // region 0, later reused as attn-out O
  short* wqT = (short*)(ws + SZ);                 // wqT|wkT|wvT contiguous (BtAll)
  short* wkT = wqT + (size_t)DIM * DIM;
  short* wvT = wkT + (size_t)DIM * DIM;
  short* woT = wvT + (size_t)DIM * DIM;
  short *Qp, *Kp, *Vp;
  if (ws_size >= 5 * SZ) {
    Qp = (short*)(ws + 2 * SZ);
    Kp = (short*)(ws + 3 * SZ);
    Vp = (short*)(ws + 4 * SZ);
  } else {                                        // park Q,K in d_out (overwritten at the end)
    Qp = (short*)d_out;
    Kp = (short*)d_out + SZ / 2;
    Vp = (short*)(ws + 2 * SZ);
  }
  short* Ob = xb;                                 // alias: xb dead after QKV GEMM

  k_convert_x<<<8192, 256, 0, stream>>>(x, xb);
  k_transpose_w<<<dim3(64, 64, 4), dim3(32, 8), 0, stream>>>(wq, wk, wv, wo,
                                                             wqT, wkT, wvT, woT);
  k_gemm_qkv<<<3072, 256, 0, stream>>>(xb, wqT, cosg, sing, Qp, Kp, Vp);
  k_flash<<<2048, 256, 0, stream>>>(Qp, Kp, Vp, Ob);
  k_gemm_out<<<1024, 256, 0, stream>>>(Ob, woT, (float*)d_out);
}